// Round 10
// baseline (661.335 us; speedup 1.0000x reference)
//
#include <hip/hip_runtime.h>
#include <math.h>

#define T_MAXX 128
#define BATCHN 64
#define NC     32
#define NCP    33          // padded ext row stride
#define BW     16
#define BLANKC 31
#define NEGF   (-1e30f)

typedef unsigned long long u64;
typedef unsigned int u32;

static const u64 PA_C = 0x100000001B3ULL;          // FNV prime
static const u64 PB_C = 6364136223846793005ULL;    // LCG multiplier

// single-wave block: HW executes a wave's LDS ops in order; only the
// compiler must be stopped from reordering across phases.
#define FENCE() asm volatile("" ::: "memory")

__device__ __forceinline__ float xexp(float x)  { return expf(x); }
__device__ __forceinline__ float xlog(float x)  { return logf(x); }
__device__ __forceinline__ float xlog1p(float x){ return log1pf(x); }

__device__ __forceinline__ float logaddexpf_(float a, float b) {
    float m = fmaxf(a, b);
    float d = fabsf(a - b);
    return m + xlog1p(xexp(-d));
}

// ---- DPP / swizzle cross-lane helpers ----
template<int C>
__device__ __forceinline__ float fdpp_keep(float v) {
    return __int_as_float(__builtin_amdgcn_update_dpp(
        __float_as_int(v), __float_as_int(v), C, 0xF, 0xF, false));
}
template<int C>
__device__ __forceinline__ float fdpp_zero(float v) {
    return __int_as_float(__builtin_amdgcn_update_dpp(
        0, __float_as_int(v), C, 0xF, 0xF, true));
}
template<int C>
__device__ __forceinline__ u32 udpp_keep(u32 v) {
    return (u32)__builtin_amdgcn_update_dpp((int)v, (int)v, C, 0xF, 0xF, false);
}

// ---- f64-packed keys: exponent 0x3FF, mantissa = (score_u32 << 10) | inv_idx10.
// Same-exponent positive doubles order exactly by the 42-bit payload, so
// v_max_f64 / v_min_f64 implement the (score, lower-idx-wins) order in ONE op.
__device__ __forceinline__ double dkey_pack(u32 u, u32 inv10) {
    u64 p = 0x3FF0000000000000ULL | ((u64)u << 10) | (u64)inv10;
    return __longlong_as_double((long long)p);
}
template<int C>
__device__ __forceinline__ double ddpp_keep(double v) {
    u64 b = (u64)__double_as_longlong(v);
    u32 lo = udpp_keep<C>((u32)b);
    u32 hi = udpp_keep<C>((u32)(b >> 32));
    return __longlong_as_double((long long)(((u64)hi << 32) | lo));
}
template<int P>
__device__ __forceinline__ double dswz(double v) {
    u64 b = (u64)__double_as_longlong(v);
    u32 lo = (u32)__builtin_amdgcn_ds_swizzle((int)(u32)b, P);
    u32 hi = (u32)__builtin_amdgcn_ds_swizzle((int)(u32)(b >> 32), P);
    return __longlong_as_double((long long)(((u64)hi << 32) | lo));
}
__device__ __forceinline__ double dbperm(double v, int srcl) {
    u64 b = (u64)__double_as_longlong(v);
    u32 lo = (u32)__builtin_amdgcn_ds_bpermute(srcl << 2, (int)(u32)b);
    u32 hi = (u32)__builtin_amdgcn_ds_bpermute(srcl << 2, (int)(u32)(b >> 32));
    return __longlong_as_double((long long)(((u64)hi << 32) | lo));
}

extern "C" __global__ void __launch_bounds__(64)
CTCPredictionsCpu_kernel(const float* __restrict__ data,
                         const int* __restrict__ dlen,
                         int* __restrict__ out)
{
    const int b      = blockIdx.x;
    const int tid    = threadIdx.x;
    const int length = dlen[b];
    const int lane_c = tid & 31;
    const int lane_h = tid >> 5;
    const int lane_g = tid & 15;     // lane within group
    const int grp    = tid >> 4;     // candidate group 0..3

    __shared__ float logpS[T_MAXX][NC];    // precomputed log-softmax
    __shared__ float ext[BW][NCP];
    __shared__ int   lensS[BW], lastS[BW];
    __shared__ float lpBS[BW], lpTotS[BW];
    __shared__ float stayBS[BW], stayNBS[BW];
    __shared__ u64   hAS[BW], hBS[BW];     // raw hashes
    __shared__ u64   hAXS[BW], hBXS[BW];   // pre-multiplied: h * P
    __shared__ int   trace[T_MAXX][BW];    // src | char<<8 | is_ext<<16
    __shared__ int   outbuf[T_MAXX];

    // ---- pre-pass: log_softmax for ALL frames (2 frames/iter, pipelined).
    #pragma unroll 4
    for (int f0 = 0; f0 < T_MAXX; f0 += 2) {
        int f = f0 + lane_h;
        float x = data[((size_t)f * BATCHN + b) * NC + lane_c];
        float mm = x;
        mm = fmaxf(mm, fdpp_keep<0xB1>(mm));
        mm = fmaxf(mm, fdpp_keep<0x4E>(mm));
        mm = fmaxf(mm, fdpp_keep<0x141>(mm));
        mm = fmaxf(mm, fdpp_keep<0x140>(mm));
        { float o = __int_as_float(
              __builtin_amdgcn_ds_swizzle(__float_as_int(mm), 0x401F)); // xor16
          mm = fmaxf(mm, o); }
        float e = xexp(x - mm);
        float ss = e;
        ss += fdpp_zero<0xB1>(ss);
        ss += fdpp_zero<0x4E>(ss);
        ss += fdpp_zero<0x141>(ss);
        ss += fdpp_zero<0x140>(ss);
        { float o = __int_as_float(
              __builtin_amdgcn_ds_swizzle(__float_as_int(ss), 0x401F));
          ss += o; }
        float ls2 = xlog(ss);
        logpS[f][lane_c] = (x - mm) - ls2;
    }
    FENCE();

    // beam state in registers of lanes 0..15 (lane j owns beam j)
    int   myLen  = 0;
    int   myLast = -1;
    float myLpB  = (tid == 0) ? 0.0f : NEGF;
    float myLpNB = NEGF;
    u64   myHA   = 1, myHB = 1;

    for (int t = 0; t < length; ++t) {
        float mylogp  = logpS[t][lane_c];
        float lpBlank = logpS[t][BLANKC];

        // ---- stay candidates + publish state to LDS ----
        float myTot = 0.0f, stayB = 0.0f, stayNB = 0.0f;
        if (tid < BW) {
            myTot = logaddexpf_(myLpB, myLpNB);
            float lp_last = logpS[t][(myLast >= 0) ? myLast : 0];
            stayB  = myTot + lpBlank;
            stayNB = (myLen > 0) ? (myLpNB + lp_last) : NEGF;
            lensS[tid]  = myLen;
            lastS[tid]  = myLast;
            lpBS[tid]   = myLpB;
            lpTotS[tid] = myTot;
            stayBS[tid] = stayB;
            hAS[tid]    = myHA;
            hBS[tid]    = myHB;
            hAXS[tid]   = myHA * PA_C;
            hBXS[tid]   = myHB * PB_C;
        }
        FENCE();

        // ---- ext[i][c]: lane owns col lane_c, rows i = 2*s8 + lane_h ----
        #pragma unroll
        for (int s8 = 0; s8 < 8; ++s8) {
            int i = 2 * s8 + lane_h;
            float base = (lane_c == lastS[i]) ? lpBS[i] : lpTotS[i];
            float v = base + mylogp;
            if (lane_c == BLANKC) v = NEGF;
            ext[i][lane_c] = v;
        }
        FENCE();

        // ---- merge ext(i,c) into stay(j).
        // Beams hold DISTINCT valid prefixes for all t>=1 => at most ONE i
        // matches j; logsumexp of one element is the element (xlog(1)==0).
        float staySc = NEGF;
        if (tid < BW) {
            bool valid = myTot > -5e29f;
            if (valid && myLen > 0) {
                const int cj = myLast;
                const u64 wantA = myHA - (u64)(cj + 1);  // hAXS[i] == wantA
                const u64 wantB = myHB - (u64)(cj + 1);
                u32 mmask = 0;
                #pragma unroll
                for (int i = 0; i < BW; ++i) {
                    bool hit = (hAXS[i] == wantA) && (hBXS[i] == wantB);
                    mmask |= hit ? (1u << i) : 0u;
                }
                if (mmask) {
                    int i0 = __ffs(mmask) - 1;
                    float merged = ext[i0][cj];
                    ext[i0][cj] = NEGF;                  // consume (disjoint cells)
                    stayNB = logaddexpf_(stayNB, merged);
                }
            }
            stayNBS[tid] = stayNB;                       // post-merge publish
            staySc = logaddexpf_(stayB, stayNB);
        }
        FENCE();

        // ---- keys, group-partitioned: group g owns ext rows 4g..4g+3;
        //      stays live in group 0 slot 8.
        double K[16];
        #pragma unroll
        for (int j = 0; j < 8; ++j) {
            int r = 4 * grp + (j >> 1);
            int c = lane_g + ((j & 1) << 4);
            u32 uu = __float_as_uint(ext[r][c]);        // post-merge value
            uu = (uu & 0x80000000u) ? ~uu : (uu | 0x80000000u);
            K[j] = dkey_pack(uu, 1023u - (u32)(BW + r * NC + c));
        }
        if (grp == 0) {
            u32 u = __float_as_uint(staySc);
            u = (u & 0x80000000u) ? ~u : (u | 0x80000000u);
            K[8] = dkey_pack(u, 1023u - (u32)lane_g);
        } else {
            K[8] = 0.0;
        }

        // ---- per-lane sort 9 desc (Batcher-8 + insertion), pad to 16 ----
        #define CE(a,bb) { double hi_ = fmax(K[a], K[bb]); \
                           double lo_ = fmin(K[a], K[bb]); \
                           K[a] = hi_; K[bb] = lo_; }
        CE(0,1) CE(2,3) CE(4,5) CE(6,7)
        CE(0,2) CE(1,3) CE(4,6) CE(5,7)
        CE(1,2) CE(5,6)
        CE(0,4) CE(1,5) CE(2,6) CE(3,7)
        CE(2,4) CE(3,5)
        CE(1,2) CE(3,4) CE(5,6)
        CE(7,8) CE(6,7) CE(5,6) CE(4,5) CE(3,4) CE(2,3) CE(1,2) CE(0,1)
        #undef CE
        #pragma unroll
        for (int j = 9; j < 16; ++j) K[j] = 0.0;

        // ---- global top-16 via bitonic merge cascade (6 levels).
        // Each level: partner's reversed list via cross-lane fetch, keep
        // elementwise max (bitonic half-cleaner => top-16 of union), then
        // 4-level bitonic cleanup. All lanes converge to the SAME sorted
        // global top-16 (keys distinct; order = exact JAX tie-break).
        #define CEM(a,bb) { double hi_ = fmax(M[a], M[bb]); \
                            double lo_ = fmin(M[a], M[bb]); \
                            M[a] = hi_; M[bb] = lo_; }
        #define CLEANUP() \
            CEM(0,8) CEM(1,9) CEM(2,10) CEM(3,11) CEM(4,12) CEM(5,13) CEM(6,14) CEM(7,15) \
            CEM(0,4) CEM(1,5) CEM(2,6)  CEM(3,7)  CEM(8,12) CEM(9,13) CEM(10,14) CEM(11,15) \
            CEM(0,2) CEM(1,3) CEM(4,6)  CEM(5,7)  CEM(8,10) CEM(9,11) CEM(12,14) CEM(13,15) \
            CEM(0,1) CEM(2,3) CEM(4,5)  CEM(6,7)  CEM(8,9)  CEM(10,11) CEM(12,13) CEM(14,15)
        #define MERGE_DPP(CTRL) { \
            double M[16]; \
            _Pragma("unroll") \
            for (int i = 0; i < 16; ++i) M[i] = fmax(K[i], ddpp_keep<CTRL>(K[15 - i])); \
            CLEANUP() \
            _Pragma("unroll") \
            for (int i = 0; i < 16; ++i) K[i] = M[i]; \
        }
        MERGE_DPP(0xB1)    // xor1  (quad_perm [1,0,3,2])
        MERGE_DPP(0x4E)    // xor2  (quad_perm [2,3,0,1])
        MERGE_DPP(0x141)   // clusters of 4 <-> 4 (row_half_mirror)
        MERGE_DPP(0x140)   // clusters of 8 <-> 8 (row_mirror)
        {                  // clusters of 16 <-> 16 (ds_swizzle xor16)
            double M[16];
            #pragma unroll
            for (int i = 0; i < 16; ++i) M[i] = fmax(K[i], dswz<0x401F>(K[15 - i]));
            CLEANUP()
            #pragma unroll
            for (int i = 0; i < 16; ++i) K[i] = M[i];
        }
        {                  // halves 32 <-> 32 (ds_bpermute xor32)
            double M[16];
            #pragma unroll
            for (int i = 0; i < 16; ++i) M[i] = fmax(K[i], dbperm(K[15 - i], tid ^ 32));
            CLEANUP()
            #pragma unroll
            for (int i = 0; i < 16; ++i) K[i] = M[i];
        }
        #undef MERGE_DPP
        #undef CLEANUP
        #undef CEM

        // ---- lane j takes global rank-j key (cndmask tree, static indices) ----
        double T8[8], T4[4], T2[2], Tw;
        #pragma unroll
        for (int i = 0; i < 8; ++i) T8[i] = (lane_g & 8) ? K[i + 8] : K[i];
        #pragma unroll
        for (int i = 0; i < 4; ++i) T4[i] = (lane_g & 4) ? T8[i + 4] : T8[i];
        #pragma unroll
        for (int i = 0; i < 2; ++i) T2[i] = (lane_g & 2) ? T4[i + 2] : T4[i];
        Tw = (lane_g & 1) ? T2[1] : T2[0];
        int myidx = 1023 - (int)((u64)__double_as_longlong(Tw) & 1023ULL);

        // ---- state update ----
        bool isext = (tid < BW) && (myidx >= BW);
        int  istay = (tid < BW && !isext) ? myidx : 0;
        if (tid < BW) {
            int e2 = isext ? (myidx - BW) : 0;
            int ie = e2 >> 5, ce = e2 & 31;
            int src = isext ? ie : istay;
            int  sLen  = lensS[src];
            int  sLast = lastS[src];
            u64  sHA   = hAS[src], sHB = hBS[src];
            u64  sHAX  = hAXS[src], sHBX = hBXS[src];
            float extv = ext[ie][ce];
            float gB   = stayBS[istay];
            float gNB  = stayNBS[istay];
            myLen  = sLen + (isext ? 1 : 0);
            myLast = isext ? ce : sLast;
            myLpB  = isext ? NEGF : gB;
            myLpNB = isext ? extv : gNB;
            myHA   = isext ? (sHAX + (u64)(ce + 1)) : sHA;
            myHB   = isext ? (sHBX + (u64)(ce + 1)) : sHB;
            trace[t][tid] = src | (ce << 8) | (isext ? (1 << 16) : 0);
        }
        FENCE();
    }

    // ---- backtrack beam 0 (lane 0 holds its length) ----
    FENCE();
    for (int l = tid; l < T_MAXX; l += 64) outbuf[l] = 0;
    FENCE();
    if (tid == 0) {
        int cur = 0;
        int pos = myLen - 1;
        for (int s = length - 1; s >= 0; --s) {
            int e = trace[s][cur];
            if (e & (1 << 16)) outbuf[pos--] = (e >> 8) & 0xFF;
            cur = e & 0xFF;
        }
    }
    FENCE();
    for (int l = tid; l < T_MAXX; l += 64) out[b * T_MAXX + l] = outbuf[l];
}

extern "C" void kernel_launch(void* const* d_in, const int* in_sizes, int n_in,
                              void* d_out, int out_size, void* d_ws, size_t ws_size,
                              hipStream_t stream) {
    const float* data = (const float*)d_in[0];
    const int*   dlen = (const int*)d_in[1];
    int*         out  = (int*)d_out;
    hipLaunchKernelGGL(CTCPredictionsCpu_kernel, dim3(BATCHN), dim3(64), 0, stream,
                       data, dlen, out);
}

// Round 12
// 450.690 us; speedup vs baseline: 1.4674x; 1.4674x over previous
//
#include <hip/hip_runtime.h>
#include <math.h>

#define T_MAXX 128
#define BATCHN 64
#define NC     32
#define NCP    34          // padded ext row stride (even -> 8B-aligned b64 reads)
#define BW     16
#define BLANKC 31
#define NEGF   (-1e30f)

typedef unsigned long long u64;
typedef unsigned int u32;

static const u64 PA_C = 0x100000001B3ULL;          // FNV prime

// single-wave block: HW executes a wave's LDS ops in order; only the
// compiler must be stopped from reordering across phases.
#define FENCE() asm volatile("" ::: "memory")

__device__ __forceinline__ float xexp(float x)  { return expf(x); }
__device__ __forceinline__ float xlog(float x)  { return logf(x); }
__device__ __forceinline__ float xlog1p(float x){ return log1pf(x); }

__device__ __forceinline__ float logaddexpf_(float a, float b) {
    float m = fmaxf(a, b);
    float d = fabsf(a - b);
    return m + xlog1p(xexp(-d));
}

// ---- DPP / swizzle cross-lane helpers ----
template<int C>
__device__ __forceinline__ float fdpp_keep(float v) {
    return __int_as_float(__builtin_amdgcn_update_dpp(
        __float_as_int(v), __float_as_int(v), C, 0xF, 0xF, false));
}
template<int C>
__device__ __forceinline__ float fdpp_zero(float v) {
    return __int_as_float(__builtin_amdgcn_update_dpp(
        0, __float_as_int(v), C, 0xF, 0xF, true));
}
template<int C>
__device__ __forceinline__ u32 udpp_keep(u32 v) {
    return (u32)__builtin_amdgcn_update_dpp((int)v, (int)v, C, 0xF, 0xF, false);
}

// ---- f64-packed keys: exponent 0x3FF, mantissa = (score_u32 << 10) | inv_idx10.
// Same-exponent positive doubles order exactly by the 42-bit payload, so
// v_max_f64 / v_min_f64 implement the (score, lower-idx-wins) order in ONE op.
__device__ __forceinline__ double dkey_pack(u32 u, u32 inv10) {
    u64 p = 0x3FF0000000000000ULL | ((u64)u << 10) | (u64)inv10;
    return __longlong_as_double((long long)p);
}
__device__ __forceinline__ u32 score_bits(float sc) {
    u32 u = __float_as_uint(sc);
    return (u & 0x80000000u) ? ~u : (u | 0x80000000u);
}
template<int C>
__device__ __forceinline__ double ddpp_keep(double v) {
    u64 b = (u64)__double_as_longlong(v);
    u32 lo = udpp_keep<C>((u32)b);
    u32 hi = udpp_keep<C>((u32)(b >> 32));
    return __longlong_as_double((long long)(((u64)hi << 32) | lo));
}
template<int P>
__device__ __forceinline__ double dswz(double v) {
    u64 b = (u64)__double_as_longlong(v);
    u32 lo = (u32)__builtin_amdgcn_ds_swizzle((int)(u32)b, P);
    u32 hi = (u32)__builtin_amdgcn_ds_swizzle((int)(u32)(b >> 32), P);
    return __longlong_as_double((long long)(((u64)hi << 32) | lo));
}
__device__ __forceinline__ double dbperm(double v, int srcl) {
    u64 b = (u64)__double_as_longlong(v);
    u32 lo = (u32)__builtin_amdgcn_ds_bpermute(srcl << 2, (int)(u32)b);
    u32 hi = (u32)__builtin_amdgcn_ds_bpermute(srcl << 2, (int)(u32)(b >> 32));
    return __longlong_as_double((long long)(((u64)hi << 32) | lo));
}
// 16-lane all-broadcast key max: 4 DPP+max stages
__device__ __forceinline__ double grp16_dmax(double m) {
    m = fmax(m, ddpp_keep<0xB1>(m));    // xor1
    m = fmax(m, ddpp_keep<0x4E>(m));    // xor2
    m = fmax(m, ddpp_keep<0x141>(m));   // other quad of 8
    m = fmax(m, ddpp_keep<0x140>(m));   // other 8 of 16
    return m;
}
// compare-exchange step of the bitonic merge
__device__ __forceinline__ void dce(double &m, double o, bool keepmax) {
    double mx = fmax(m, o), mn = fmin(m, o);
    m = keepmax ? mx : mn;
}

extern "C" __global__ void __launch_bounds__(64)
CTCPredictionsCpu_kernel(const float* __restrict__ data,
                         const int* __restrict__ dlen,
                         int* __restrict__ out)
{
    const int b      = blockIdx.x;
    const int tid    = threadIdx.x;
    const int length = dlen[b];
    const int lane_c = tid & 31;
    const int lane_h = tid >> 5;
    const int lane_g = tid & 15;     // lane within group
    const int grp    = tid >> 4;     // candidate group 0..3

    __shared__ float logpS[T_MAXX][NC];    // precomputed log-softmax
    __shared__ float ext[BW][NCP];
    __shared__ int4  S4[BW];               // {last, bits(lpB), bits(lpTot), lens}
    __shared__ ulonglong2 HH[BW];          // {hA, hA*PA}
    __shared__ float stayBS[BW], stayNBS[BW];
    __shared__ int   trace[T_MAXX][BW];    // src | char<<8 | is_ext<<16
    __shared__ int   outbuf[T_MAXX];

    // ---- pre-pass: log_softmax for ALL frames (2 frames/iter, pipelined).
    #pragma unroll 4
    for (int f0 = 0; f0 < T_MAXX; f0 += 2) {
        int f = f0 + lane_h;
        float x = data[((size_t)f * BATCHN + b) * NC + lane_c];
        float mm = x;
        mm = fmaxf(mm, fdpp_keep<0xB1>(mm));
        mm = fmaxf(mm, fdpp_keep<0x4E>(mm));
        mm = fmaxf(mm, fdpp_keep<0x141>(mm));
        mm = fmaxf(mm, fdpp_keep<0x140>(mm));
        { float o = __int_as_float(
              __builtin_amdgcn_ds_swizzle(__float_as_int(mm), 0x401F)); // xor16
          mm = fmaxf(mm, o); }
        float e = xexp(x - mm);
        float ss = e;
        ss += fdpp_zero<0xB1>(ss);
        ss += fdpp_zero<0x4E>(ss);
        ss += fdpp_zero<0x141>(ss);
        ss += fdpp_zero<0x140>(ss);
        { float o = __int_as_float(
              __builtin_amdgcn_ds_swizzle(__float_as_int(ss), 0x401F));
          ss += o; }
        float ls2 = xlog(ss);
        logpS[f][lane_c] = (x - mm) - ls2;
    }
    FENCE();

    // beam state in registers of lanes 0..15 (lane j owns beam j)
    int   myLen  = 0;
    int   myLast = -1;
    float myLpB  = (tid == 0) ? 0.0f : NEGF;
    float myLpNB = NEGF;
    u64   myHA   = 1;

    float lp_cur = logpS[0][lane_c];       // register-carried logp of class lane_c

    for (int t = 0; t < length; ++t) {
        float mylogp  = lp_cur;
        float lpBlank = __int_as_float(
            __builtin_amdgcn_readlane(__float_as_int(mylogp), 31));
        // prefetch next frame's logp early; consumed next iteration (register)
        int   tn      = (t + 1 < length) ? t + 1 : t;
        float lp_nxt  = logpS[tn][lane_c];

        // ---- stay candidates + publish state to LDS (packed) ----
        float myTot = 0.0f, stayB = 0.0f, stayNB = 0.0f;
        if (tid < BW) {
            myTot = logaddexpf_(myLpB, myLpNB);
            float lp_last = logpS[t][(myLast >= 0) ? myLast : 0];
            stayB  = myTot + lpBlank;
            stayNB = (myLen > 0) ? (myLpNB + lp_last) : NEGF;
            S4[tid] = make_int4(myLast, __float_as_int(myLpB),
                                __float_as_int(myTot), myLen);
            HH[tid] = make_ulonglong2(myHA, myHA * PA_C);
            stayBS[tid] = stayB;
        }
        FENCE();

        // ---- ext[i][c]: lane owns col lane_c, rows i = 2*s8 + lane_h ----
        #pragma unroll
        for (int s8 = 0; s8 < 8; ++s8) {
            int i = 2 * s8 + lane_h;
            int4 s = S4[i];                          // one ds_read_b128
            float base = (lane_c == s.x) ? __int_as_float(s.y)
                                         : __int_as_float(s.z);
            float v = base + mylogp;
            if (lane_c == BLANKC) v = NEGF;
            ext[i][lane_c] = v;
        }
        FENCE();

        // ---- merge ext(i,c) into stay(j).
        // Beams hold DISTINCT valid prefixes for all t>=1 => at most ONE i
        // matches j; logsumexp of one element is the element (xlog(1)==0).
        // 64-bit rolling hash identity: parent hash * PA == myHA - (cj+1).
        float staySc = NEGF;
        if (tid < BW) {
            if (myLen > 0) {
                const int cj = myLast;
                const u64 want = myHA - (u64)(cj + 1);   // == HH[i].y on match
                u32 mmask = 0;
                #pragma unroll
                for (int i = 0; i < BW; ++i) {
                    bool hit = (HH[i].y == want);
                    mmask |= hit ? (1u << i) : 0u;
                }
                if (mmask) {
                    int i0 = __ffs(mmask) - 1;
                    float merged = ext[i0][cj];
                    ext[i0][cj] = NEGF;                  // consume (disjoint cells)
                    stayNB = logaddexpf_(stayNB, merged);
                }
            }
            stayNBS[tid] = stayNB;                       // post-merge publish
            staySc = logaddexpf_(stayB, stayNB);
        }
        FENCE();

        // ---- keys, group-partitioned: group g owns ext rows 4g..4g+3;
        //      lane covers adjacent cols {2*lane_g, 2*lane_g+1} (b64 loads).
        //      Stays live in group 0 slot 8.
        double K[9];
        #pragma unroll
        for (int rr = 0; rr < 4; ++rr) {
            int r = 4 * grp + rr;
            float2 p = *(const float2*)&ext[r][2 * lane_g];  // ds_read_b64
            int c0 = 2 * lane_g;
            K[2 * rr]     = dkey_pack(score_bits(p.x),
                                      1023u - (u32)(BW + r * NC + c0));
            K[2 * rr + 1] = dkey_pack(score_bits(p.y),
                                      1023u - (u32)(BW + r * NC + c0 + 1));
        }
        K[8] = (grp == 0) ? dkey_pack(score_bits(staySc), 1023u - (u32)lane_g)
                          : 0.0;

        // ---- per-lane sort 9 desc: Batcher-8 + insertion of K[8] ----
        #define CE(a,bb) { double hi_ = fmax(K[a], K[bb]); \
                           double lo_ = fmin(K[a], K[bb]); \
                           K[a] = hi_; K[bb] = lo_; }
        CE(0,1) CE(2,3) CE(4,5) CE(6,7)
        CE(0,2) CE(1,3) CE(4,6) CE(5,7)
        CE(1,2) CE(5,6)
        CE(0,4) CE(1,5) CE(2,6) CE(3,7)
        CE(2,4) CE(3,5)
        CE(1,2) CE(3,4) CE(5,6)
        CE(7,8) CE(6,7) CE(5,6) CE(4,5) CE(3,4) CE(2,3) CE(1,2) CE(0,1)
        #undef CE

        // ---- group tournament: 16 rounds, 4-stage DPP/f64max reduce.
        //      Progressive shift: round k>=8 shifts only depth 15-k with a
        //      zero insert (exact: K[r] must match full-shift state only for
        //      r <= 15-k-1 — window-invariant proof).
        double W = 0.0;
        #pragma unroll
        for (int k = 0; k < BW; ++k) {
            double best = grp16_dmax(K[0]);
            W = (lane_g == k) ? best : W;
            bool win = (K[0] == best);
            const int d = (k < 8) ? 8 : (15 - k);
            #pragma unroll
            for (int r = 0; r < 8; ++r)
                if (r < d) K[r] = win ? K[r + 1] : K[r];
            if (k < 15) K[d] = win ? 0.0 : K[d];
        }

        // ---- merge A: (g0,g1) on lanes 0-31 and (g2,g3) on lanes 32-63 ----
        { double o = dswz<0x7C1F>(W);    dce(W, o, (tid & 16) == 0); }
        { double o = dswz<0x201F>(W);    dce(W, o, (tid & 8)  == 0); }
        { double o = dswz<0x101F>(W);    dce(W, o, (tid & 4)  == 0); }
        { double o = ddpp_keep<0x4E>(W); dce(W, o, (tid & 2)  == 0); }
        { double o = ddpp_keep<0xB1>(W); dce(W, o, (tid & 1)  == 0); }
        // move S2 (lanes 32-47, sorted desc) into lanes 16-31
        {
            double o = dbperm(W, (tid + 16) & 63);
            W = (tid >= 16 && tid < 32) ? o : W;
        }
        // ---- merge B: final top-16 lands sorted on lanes 0-15 ----
        { double o = dswz<0x7C1F>(W);    dce(W, o, (tid & 16) == 0); }
        { double o = dswz<0x201F>(W);    dce(W, o, (tid & 8)  == 0); }
        { double o = dswz<0x101F>(W);    dce(W, o, (tid & 4)  == 0); }
        { double o = ddpp_keep<0x4E>(W); dce(W, o, (tid & 2)  == 0); }
        { double o = ddpp_keep<0xB1>(W); dce(W, o, (tid & 1)  == 0); }
        int myidx = 1023 - (int)((u64)__double_as_longlong(W) & 1023ULL);

        // ---- state update ----
        bool isext = (tid < BW) && (myidx >= BW);
        int  istay = (tid < BW && !isext) ? myidx : 0;
        if (tid < BW) {
            int e2 = isext ? (myidx - BW) : 0;
            int ie = e2 >> 5, ce = e2 & 31;
            int src = isext ? ie : istay;
            int4       s  = S4[src];                 // b128: last,lpB,lpTot,lens
            ulonglong2 hh = HH[src];                 // b128: hA, hA*PA
            float extv = ext[ie][ce];
            float gB   = stayBS[istay];
            float gNB  = stayNBS[istay];
            myLen  = s.w + (isext ? 1 : 0);
            myLast = isext ? ce : s.x;
            myLpB  = isext ? NEGF : gB;
            myLpNB = isext ? extv : gNB;
            myHA   = isext ? (hh.y + (u64)(ce + 1)) : hh.x;
            trace[t][tid] = src | (ce << 8) | (isext ? (1 << 16) : 0);
        }
        FENCE();

        lp_cur = lp_nxt;
    }

    // ---- backtrack beam 0 (lane 0 holds its length) ----
    FENCE();
    for (int l = tid; l < T_MAXX; l += 64) outbuf[l] = 0;
    FENCE();
    if (tid == 0) {
        int cur = 0;
        int pos = myLen - 1;
        for (int s = length - 1; s >= 0; --s) {
            int e = trace[s][cur];
            if (e & (1 << 16)) outbuf[pos--] = (e >> 8) & 0xFF;
            cur = e & 0xFF;
        }
    }
    FENCE();
    for (int l = tid; l < T_MAXX; l += 64) out[b * T_MAXX + l] = outbuf[l];
}

extern "C" void kernel_launch(void* const* d_in, const int* in_sizes, int n_in,
                              void* d_out, int out_size, void* d_ws, size_t ws_size,
                              hipStream_t stream) {
    const float* data = (const float*)d_in[0];
    const int*   dlen = (const int*)d_in[1];
    int*         out  = (int*)d_out;
    hipLaunchKernelGGL(CTCPredictionsCpu_kernel, dim3(BATCHN), dim3(64), 0, stream,
                       data, dlen, out);
}

// Round 13
// 421.832 us; speedup vs baseline: 1.5678x; 1.0684x over previous
//
#include <hip/hip_runtime.h>
#include <math.h>

#define T_MAXX 128
#define BATCHN 64
#define NC     32
#define NCP    34          // padded ext row stride (even -> 8B-aligned b64 reads)
#define BW     16
#define BLANKC 31
#define NEGF   (-1e30f)

typedef unsigned long long u64;
typedef unsigned int u32;

static const u64 PA_C = 0x100000001B3ULL;          // FNV prime

// single-wave block: HW executes a wave's LDS ops in order; only the
// compiler must be stopped from reordering across phases.
#define FENCE() asm volatile("" ::: "memory")

__device__ __forceinline__ float xexp(float x)  { return expf(x); }
__device__ __forceinline__ float xlog(float x)  { return logf(x); }
__device__ __forceinline__ float xlog1p(float x){ return log1pf(x); }

__device__ __forceinline__ float logaddexpf_(float a, float b) {
    float m = fmaxf(a, b);
    float d = fabsf(a - b);
    return m + xlog1p(xexp(-d));
}

// ---- DPP / swizzle / readlane cross-lane helpers ----
template<int C>
__device__ __forceinline__ float fdpp_keep(float v) {
    return __int_as_float(__builtin_amdgcn_update_dpp(
        __float_as_int(v), __float_as_int(v), C, 0xF, 0xF, false));
}
template<int C>
__device__ __forceinline__ float fdpp_zero(float v) {
    return __int_as_float(__builtin_amdgcn_update_dpp(
        0, __float_as_int(v), C, 0xF, 0xF, true));
}
template<int C>
__device__ __forceinline__ u32 udpp_keep(u32 v) {
    return (u32)__builtin_amdgcn_update_dpp((int)v, (int)v, C, 0xF, 0xF, false);
}
__device__ __forceinline__ u64 rl64(u64 v, int l) {
    u32 lo = (u32)__builtin_amdgcn_readlane((int)(u32)v, l);
    u32 hi = (u32)__builtin_amdgcn_readlane((int)(u32)(v >> 32), l);
    return ((u64)hi << 32) | lo;
}

// ---- f64-packed keys: exponent 0x3FF, mantissa = (score_u32 << 10) | inv_idx10.
// Same-exponent positive doubles order exactly by the 42-bit payload, so
// v_max_f64 / v_min_f64 implement the (score, lower-idx-wins) order in ONE op.
__device__ __forceinline__ double dkey_pack(u32 u, u32 inv10) {
    u64 p = 0x3FF0000000000000ULL | ((u64)u << 10) | (u64)inv10;
    return __longlong_as_double((long long)p);
}
__device__ __forceinline__ u32 score_bits(float sc) {
    u32 u = __float_as_uint(sc);
    return (u & 0x80000000u) ? ~u : (u | 0x80000000u);
}
template<int C>
__device__ __forceinline__ double ddpp_keep(double v) {
    u64 b = (u64)__double_as_longlong(v);
    u32 lo = udpp_keep<C>((u32)b);
    u32 hi = udpp_keep<C>((u32)(b >> 32));
    return __longlong_as_double((long long)(((u64)hi << 32) | lo));
}
template<int P>
__device__ __forceinline__ double dswz(double v) {
    u64 b = (u64)__double_as_longlong(v);
    u32 lo = (u32)__builtin_amdgcn_ds_swizzle((int)(u32)b, P);
    u32 hi = (u32)__builtin_amdgcn_ds_swizzle((int)(u32)(b >> 32), P);
    return __longlong_as_double((long long)(((u64)hi << 32) | lo));
}
__device__ __forceinline__ double dbperm(double v, int srcl) {
    u64 b = (u64)__double_as_longlong(v);
    u32 lo = (u32)__builtin_amdgcn_ds_bpermute(srcl << 2, (int)(u32)b);
    u32 hi = (u32)__builtin_amdgcn_ds_bpermute(srcl << 2, (int)(u32)(b >> 32));
    return __longlong_as_double((long long)(((u64)hi << 32) | lo));
}
// 16-lane all-broadcast key max: 4 DPP+max stages
__device__ __forceinline__ double grp16_dmax(double m) {
    m = fmax(m, ddpp_keep<0xB1>(m));    // xor1
    m = fmax(m, ddpp_keep<0x4E>(m));    // xor2
    m = fmax(m, ddpp_keep<0x141>(m));   // other quad of 8
    m = fmax(m, ddpp_keep<0x140>(m));   // other 8 of 16
    return m;
}
// compare-exchange step of the bitonic merge
__device__ __forceinline__ void dce(double &m, double o, bool keepmax) {
    double mx = fmax(m, o), mn = fmin(m, o);
    m = keepmax ? mx : mn;
}

extern "C" __global__ void __launch_bounds__(64)
CTCPredictionsCpu_kernel(const float* __restrict__ data,
                         const int* __restrict__ dlen,
                         int* __restrict__ out)
{
    const int b      = blockIdx.x;
    const int tid    = threadIdx.x;
    const int length = dlen[b];
    const int lane_c = tid & 31;
    const int lane_h = tid >> 5;
    const int lane_g = tid & 15;     // lane within group
    const int grp    = tid >> 4;     // candidate group 0..3

    __shared__ float logpS[T_MAXX][NC];    // precomputed log-softmax
    __shared__ float ext[BW][NCP];
    __shared__ int4  S4[BW];               // {last, bits(lpB), bits(lpTot), lens}
    __shared__ ulonglong2 HH[BW];          // {hA, hA*PA}
    __shared__ float stayBS[BW], stayNBS[BW], stayScS[BW];
    __shared__ int   trace[T_MAXX][BW];    // src | char<<8 | is_ext<<16
    __shared__ int   outbuf[T_MAXX];

    // ---- pre-pass: log_softmax for ALL frames (2 frames/iter, pipelined).
    #pragma unroll 4
    for (int f0 = 0; f0 < T_MAXX; f0 += 2) {
        int f = f0 + lane_h;
        float x = data[((size_t)f * BATCHN + b) * NC + lane_c];
        float mm = x;
        mm = fmaxf(mm, fdpp_keep<0xB1>(mm));
        mm = fmaxf(mm, fdpp_keep<0x4E>(mm));
        mm = fmaxf(mm, fdpp_keep<0x141>(mm));
        mm = fmaxf(mm, fdpp_keep<0x140>(mm));
        { float o = __int_as_float(
              __builtin_amdgcn_ds_swizzle(__float_as_int(mm), 0x401F)); // xor16
          mm = fmaxf(mm, o); }
        float e = xexp(x - mm);
        float ss = e;
        ss += fdpp_zero<0xB1>(ss);
        ss += fdpp_zero<0x4E>(ss);
        ss += fdpp_zero<0x141>(ss);
        ss += fdpp_zero<0x140>(ss);
        { float o = __int_as_float(
              __builtin_amdgcn_ds_swizzle(__float_as_int(ss), 0x401F));
          ss += o; }
        float ls2 = xlog(ss);
        logpS[f][lane_c] = (x - mm) - ls2;
    }
    FENCE();

    // beam state in registers of lanes 0..15 (lane j owns beam j)
    int   myLen  = 0;
    int   myLast = -1;
    float myLpB  = (tid == 0) ? 0.0f : NEGF;
    float myLpNB = NEGF;
    float myTot  = (tid == 0) ? 0.0f : NEGF;   // carried: = logaddexp(lpB,lpNB)
    u64   myHA   = 1;

    float lp_cur = logpS[0][lane_c];       // register-carried logp of class lane_c

    for (int t = 0; t < length; ++t) {
        float mylogp  = lp_cur;
        float lpBlank = __int_as_float(
            __builtin_amdgcn_readlane(__float_as_int(mylogp), 31));
        int   tn      = (t + 1 < length) ? t + 1 : t;
        float lp_nxt  = logpS[tn][lane_c];

        u64 myHAX = myHA * PA_C;           // all lanes (valid 0..15), readlane src

        // ---- stay candidates (no top-of-loop logaddexp: myTot carried) ----
        float stayB = 0.0f, stayNB = 0.0f;
        if (tid < BW) {
            float lp_last = logpS[t][(myLast >= 0) ? myLast : 0];
            stayB  = myTot + lpBlank;
            stayNB = (myLen > 0) ? (myLpNB + lp_last) : NEGF;
            S4[tid] = make_int4(myLast, __float_as_int(myLpB),
                                __float_as_int(myTot), myLen);
            HH[tid] = make_ulonglong2(myHA, myHAX);
        }
        FENCE();

        // ---- ext[i][c]: lane owns col lane_c, rows i = 2*s8 + lane_h ----
        #pragma unroll
        for (int s8 = 0; s8 < 8; ++s8) {
            int i = 2 * s8 + lane_h;
            int4 s = S4[i];                          // one ds_read_b128
            float base = (lane_c == s.x) ? __int_as_float(s.y)
                                         : __int_as_float(s.z);
            float v = base + mylogp;
            if (lane_c == BLANKC) v = NEGF;
            ext[i][lane_c] = v;
        }
        FENCE();

        // ---- merge compares via readlane (no LDS): beams distinct for t>=1
        // => at most ONE parent i matches j; merged = ext[i][cj] exactly.
        u32 mmask = 0;
        if (tid < BW && myLen > 0) {
            const u64 want = myHA - (u64)(myLast + 1);   // == hAX of parent
            #pragma unroll
            for (int i = 0; i < BW; ++i)
                mmask |= (rl64(myHAX, i) == want) ? (1u << i) : 0u;
        }
        float merged = NEGF;
        int   i0 = -1;
        if (mmask) {
            i0 = __ffs(mmask) - 1;
            merged = ext[i0][myLast];
            ext[i0][myLast] = NEGF;                      // consume (disjoint cells)
        }
        FENCE();

        // ---- issue key loads NOW (post-consume); they drain under the
        //      post-merge logaddexp chain below ----
        const float2 q0 = *(const float2*)&ext[4 * grp + 0][2 * lane_g];
        const float2 q1 = *(const float2*)&ext[4 * grp + 1][2 * lane_g];
        const float2 q2 = *(const float2*)&ext[4 * grp + 2][2 * lane_g];
        const float2 q3 = *(const float2*)&ext[4 * grp + 3][2 * lane_g];

        float staySc = NEGF;
        if (tid < BW) {
            if (i0 >= 0) stayNB = logaddexpf_(stayNB, merged);
            staySc = logaddexpf_(stayB, stayNB);
            stayBS[tid]  = stayB;
            stayNBS[tid] = stayNB;
            stayScS[tid] = staySc;
        }

        // ---- keys: group g owns ext rows 4g..4g+3, cols {2lg, 2lg+1};
        //      stays live in group 0 slot 8.
        double K[9];
        {
            int c0 = 2 * lane_g;
            int rb = BW + (4 * grp) * NC + c0;
            K[0] = dkey_pack(score_bits(q0.x), 1023u - (u32)(rb));
            K[1] = dkey_pack(score_bits(q0.y), 1023u - (u32)(rb + 1));
            K[2] = dkey_pack(score_bits(q1.x), 1023u - (u32)(rb + NC));
            K[3] = dkey_pack(score_bits(q1.y), 1023u - (u32)(rb + NC + 1));
            K[4] = dkey_pack(score_bits(q2.x), 1023u - (u32)(rb + 2 * NC));
            K[5] = dkey_pack(score_bits(q2.y), 1023u - (u32)(rb + 2 * NC + 1));
            K[6] = dkey_pack(score_bits(q3.x), 1023u - (u32)(rb + 3 * NC));
            K[7] = dkey_pack(score_bits(q3.y), 1023u - (u32)(rb + 3 * NC + 1));
        }
        K[8] = (grp == 0) ? dkey_pack(score_bits(staySc), 1023u - (u32)lane_g)
                          : 0.0;

        // ---- per-lane sort 9 desc: Batcher-8 + insertion of K[8] ----
        #define CE(a,bb) { double hi_ = fmax(K[a], K[bb]); \
                           double lo_ = fmin(K[a], K[bb]); \
                           K[a] = hi_; K[bb] = lo_; }
        CE(0,1) CE(2,3) CE(4,5) CE(6,7)
        CE(0,2) CE(1,3) CE(4,6) CE(5,7)
        CE(1,2) CE(5,6)
        CE(0,4) CE(1,5) CE(2,6) CE(3,7)
        CE(2,4) CE(3,5)
        CE(1,2) CE(3,4) CE(5,6)
        CE(7,8) CE(6,7) CE(5,6) CE(4,5) CE(3,4) CE(2,3) CE(1,2) CE(0,1)
        #undef CE

        // ---- group tournament: 16 rounds, 4-stage DPP/f64max reduce.
        //      Progressive shift: round k>=8 shifts only depth 15-k ----
        double W = 0.0;
        #pragma unroll
        for (int k = 0; k < BW; ++k) {
            double best = grp16_dmax(K[0]);
            W = (lane_g == k) ? best : W;
            bool win = (K[0] == best);
            const int d = (k < 8) ? 8 : (15 - k);
            #pragma unroll
            for (int r = 0; r < 8; ++r)
                if (r < d) K[r] = win ? K[r + 1] : K[r];
            if (k < 15) K[d] = win ? 0.0 : K[d];
        }

        // ---- merge A: (g0,g1) on lanes 0-31 and (g2,g3) on lanes 32-63 ----
        { double o = dswz<0x7C1F>(W);    dce(W, o, (tid & 16) == 0); }
        { double o = dswz<0x201F>(W);    dce(W, o, (tid & 8)  == 0); }
        { double o = dswz<0x101F>(W);    dce(W, o, (tid & 4)  == 0); }
        { double o = ddpp_keep<0x4E>(W); dce(W, o, (tid & 2)  == 0); }
        { double o = ddpp_keep<0xB1>(W); dce(W, o, (tid & 1)  == 0); }
        // move S2 (lanes 32-47, sorted desc) into lanes 16-31
        {
            double o = dbperm(W, (tid + 16) & 63);
            W = (tid >= 16 && tid < 32) ? o : W;
        }
        // ---- merge B: final top-16 lands sorted on lanes 0-15 ----
        { double o = dswz<0x7C1F>(W);    dce(W, o, (tid & 16) == 0); }
        { double o = dswz<0x201F>(W);    dce(W, o, (tid & 8)  == 0); }
        { double o = dswz<0x101F>(W);    dce(W, o, (tid & 4)  == 0); }
        { double o = ddpp_keep<0x4E>(W); dce(W, o, (tid & 2)  == 0); }
        { double o = ddpp_keep<0xB1>(W); dce(W, o, (tid & 1)  == 0); }
        int myidx = 1023 - (int)((u64)__double_as_longlong(W) & 1023ULL);

        // ---- state update ----
        FENCE();
        bool isext = (tid < BW) && (myidx >= BW);
        int  istay = (tid < BW && !isext) ? myidx : 0;
        if (tid < BW) {
            int e2 = isext ? (myidx - BW) : 0;
            int ie = e2 >> 5, ce = e2 & 31;
            int src = isext ? ie : istay;
            int4       s  = S4[src];                 // b128: last,lpB,lpTot,lens
            ulonglong2 hh = HH[src];                 // b128: hA, hA*PA
            float extv = ext[ie][ce];
            float gB   = stayBS[istay];
            float gNB  = stayNBS[istay];
            float gSc  = stayScS[istay];
            myLen  = s.w + (isext ? 1 : 0);
            myLast = isext ? ce : s.x;
            myLpB  = isext ? NEGF : gB;
            myLpNB = isext ? extv : gNB;
            // exact: logaddexp(NEGF, extv) == extv ; logaddexp(stayB,stayNB) == staySc
            myTot  = isext ? extv : gSc;
            myHA   = isext ? (hh.y + (u64)(ce + 1)) : hh.x;
            trace[t][tid] = src | (ce << 8) | (isext ? (1 << 16) : 0);
        }
        FENCE();

        lp_cur = lp_nxt;
    }

    // ---- backtrack beam 0 (lane 0 holds its length) ----
    FENCE();
    for (int l = tid; l < T_MAXX; l += 64) outbuf[l] = 0;
    FENCE();
    if (tid == 0) {
        int cur = 0;
        int pos = myLen - 1;
        for (int s = length - 1; s >= 0; --s) {
            int e = trace[s][cur];
            if (e & (1 << 16)) outbuf[pos--] = (e >> 8) & 0xFF;
            cur = e & 0xFF;
        }
    }
    FENCE();
    for (int l = tid; l < T_MAXX; l += 64) out[b * T_MAXX + l] = outbuf[l];
}

extern "C" void kernel_launch(void* const* d_in, const int* in_sizes, int n_in,
                              void* d_out, int out_size, void* d_ws, size_t ws_size,
                              hipStream_t stream) {
    const float* data = (const float*)d_in[0];
    const int*   dlen = (const int*)d_in[1];
    int*         out  = (int*)d_out;
    hipLaunchKernelGGL(CTCPredictionsCpu_kernel, dim3(BATCHN), dim3(64), 0, stream,
                       data, dlen, out);
}